// Round 18
// baseline (135.212 us; speedup 1.0000x reference)
//
#include <hip/hip_runtime.h>
#include <math.h>

// ---------------- problem constants ----------------
#define N_TOTAL 2097024
#define HWF (1024 * 1536)

#define OFF0 0
#define OFF1 1572864
#define OFF2 1966080
#define OFF3 2064384
#define OFF4 2088960
#define OFF5 2095104
#define OFF6 2096640

// output section offsets (floats)
#define OUT_LS   (3 * HWF)
#define OUT_DEC  (6 * HWF)
#define OUT_RATE (9 * HWF)

// vector loads at dword (not natural) alignment
typedef float f4 __attribute__((ext_vector_type(4), aligned(4)));
typedef float f2 __attribute__((ext_vector_type(2), aligned(4)));
typedef float f4a16 __attribute__((ext_vector_type(4), aligned(16)));
typedef _Float16 h2 __attribute__((ext_vector_type(2)));
typedef __fp16 fp16v2 __attribute__((ext_vector_type(2)));

__device__ __forceinline__ h2 as_h2(unsigned u) {
    union { unsigned u; h2 h; } x; x.u = u; return x.h;
}
__device__ __forceinline__ h2 pkrtz(float a, float b) {
    union { fp16v2 f; h2 h; } x;
    x.f = __builtin_amdgcn_cvt_pkrtz(a, b);
    return x.h;
}
__device__ __forceinline__ float dot2f(h2 a, h2 b, float c) {
#if __has_builtin(__builtin_amdgcn_fdot2)
    return __builtin_amdgcn_fdot2(a, b, c, false);
#else
    return fmaf((float)a[0], (float)b[0], fmaf((float)a[1], (float)b[1], c));
#endif
}

// ---------------- softround (fast tanh via v_exp + v_rcp) ----------------
__device__ __forceinline__ float softround_f(float x) {
    const float INV_T = 1.0f / 0.3f;
    const float HALF_OVER_TANH = 0.53699381f; // 0.5 / tanh(0.5/0.3)
    float fl = floorf(x);
    float z = (x - fl - 0.5f) * INV_T;
    float e = __expf(2.0f * z);
    float th = 1.0f - 2.0f * __builtin_amdgcn_rcpf(e + 1.0f);
    return fl + th * HALF_OVER_TANH + 0.5f;
}

// ---------------- kernel 1: quantization (4 elems/thread) + weight pack in block 0 ----------------
__global__ void quant_pack_kernel(const float* __restrict__ l0, const float* __restrict__ l1,
                                  const float* __restrict__ l2, const float* __restrict__ l3,
                                  const float* __restrict__ l4, const float* __restrict__ l5,
                                  const float* __restrict__ l6, const float* __restrict__ noise,
                                  float* __restrict__ flat_q,
                                  const float* __restrict__ sw1, const float* __restrict__ sb1,
                                  const float* __restrict__ sw2, unsigned* __restrict__ wp) {
    int t = threadIdx.x;
    if (blockIdx.x == 0) {
        for (int i = t; i < 336; i += 256) {
            union { h2 h; unsigned u; } c;
            if (i < 192) {
                int k = i >> 2, p = i & 3;
                float x = sw1[k * 7 + 2 * p];
                float y = (p < 3) ? sw1[k * 7 + 2 * p + 1] : sb1[k];
                c.h = (h2){(_Float16)x, (_Float16)y};
            } else {
                int r = i - 192;
                int o = r / 24, kk = r - o * 24;
                c.h = (h2){(_Float16)sw2[o * 48 + 2 * kk], (_Float16)sw2[o * 48 + 2 * kk + 1]};
            }
            wp[i] = c.u;
        }
    }
    int idx = (blockIdx.x * 256 + t) * 4;
    if (idx >= N_TOTAL) return;
    const float* src;
    int base;
    if      (idx < OFF1) { src = l0; base = idx - OFF0; }
    else if (idx < OFF2) { src = l1; base = idx - OFF1; }
    else if (idx < OFF3) { src = l2; base = idx - OFF2; }
    else if (idx < OFF4) { src = l3; base = idx - OFF3; }
    else if (idx < OFF5) { src = l4; base = idx - OFF4; }
    else if (idx < OFF6) { src = l5; base = idx - OFF5; }
    else                 { src = l6; base = idx - OFF6; }
    f4a16 v = *(const f4a16*)(src + base);
    f4a16 n = *(const f4a16*)(noise + idx);
    f4a16 r;
#pragma unroll
    for (int c = 0; c < 4; c++) {
        float x = v[c] * 16.0f;
        float s1 = softround_f(x);
        r[c] = softround_f(s1 + n[c] - 0.5f);
    }
    *(f4a16*)(flat_q + idx) = r;
}

// ---------------- ARM MLP + rate from ctx (unroll 8, setprio around dense section) ----------------
__device__ __forceinline__ float arm_mlp_rate(const float ctx[16], float q,
                                              const float* __restrict__ w1, const float* __restrict__ b1,
                                              const float* __restrict__ w2, const float* __restrict__ b2,
                                              const float* __restrict__ wo, const float* __restrict__ bo) {
    __builtin_amdgcn_s_setprio(1);
    float h1[16];
#pragma unroll 8
    for (int j = 0; j < 16; j++) {
        float acc = b1[j] + ctx[j];
#pragma unroll
        for (int k = 0; k < 16; k++) acc = fmaf(w1[j * 16 + k], ctx[k], acc);
        h1[j] = fmaxf(acc, 0.0f);
    }
    float h2v[16];
#pragma unroll 8
    for (int j = 0; j < 16; j++) {
        float acc = b2[j] + h1[j];
#pragma unroll
        for (int k = 0; k < 16; k++) acc = fmaf(w2[j * 16 + k], h1[k], acc);
        h2v[j] = fmaxf(acc, 0.0f);
    }
    float mu = bo[0], ls = bo[1];
#pragma unroll
    for (int k = 0; k < 16; k++) {
        mu = fmaf(wo[k], h2v[k], mu);
        ls = fmaf(wo[16 + k], h2v[k], ls);
    }
    __builtin_amdgcn_s_setprio(0);
    ls = fminf(fmaxf(ls, -13.8155f), 13.8155f);
    float inv_scale = __expf(0.5f * ls);
    float da = (q + 0.5f) - mu;
    float db = (q - 0.5f) - mu;
    float ea = __expf(-fabsf(da) * inv_scale);
    float eb = __expf(-fabsf(db) * inv_scale);
    float la = 0.5f - 0.5f * copysignf(1.0f, da) * (ea - 1.0f);
    float lb = 0.5f - 0.5f * copysignf(1.0f, db) * (eb - 1.0f);
    float proba = fmaxf(la - lb, 1.52587890625e-05f);
    return -__log2f(proba);
}

// ---------------- ARM body (vectorized context rows) ----------------
template <int H, int W, int OFFT>
__device__ __forceinline__ void arm_body(const float* __restrict__ flat_q, int pos,
                                         const float* __restrict__ w1, const float* __restrict__ b1,
                                         const float* __restrict__ w2, const float* __restrict__ b2,
                                         const float* __restrict__ wo, const float* __restrict__ bo,
                                         float* __restrict__ rate_out) {
    if (pos >= H * W) return;
    unsigned up = (unsigned)pos;
    int y = up / (unsigned)W;
    int x = pos - y * W;
    const float* g = flat_q + OFFT + (size_t)y * W + x;

    float ctx[16];
    if (y >= 3 && x >= 3 && x <= W - 3) {
        f4 r3  = *(const f4*)(g - 3 * W - 1);
        f4 r2a = *(const f4*)(g - 2 * W - 2);
        float r2b = g[-2 * W + 2];
        f4 r1a = *(const f4*)(g - W - 3);
        f2 r1b = *(const f2*)(g - W + 1);
        f2 r0  = *(const f2*)(g - 2);
        ctx[0] = r3.x;  ctx[1] = r3.y;  ctx[2] = r3.z;
        ctx[3] = r2a.x; ctx[4] = r2a.y; ctx[5] = r2a.z; ctx[6] = r2a.w; ctx[7] = r2b;
        ctx[8] = r1a.x; ctx[9] = r1a.y; ctx[10] = r1a.z; ctx[11] = r1a.w;
        ctx[12] = r1b.x; ctx[13] = r1b.y;
        ctx[14] = r0.x; ctx[15] = r0.y;
    } else {
        const int DY[16] = {-3,-3,-3,-2,-2,-2,-2,-2,-1,-1,-1,-1,-1,-1, 0, 0};
        const int DX[16] = {-1, 0, 1,-2,-1, 0, 1, 2,-3,-2,-1, 0, 1, 2,-2,-1};
#pragma unroll
        for (int k = 0; k < 16; k++) {
            int yy = y + DY[k], xx = x + DX[k];
            ctx[k] = (yy >= 0 && yy < H && xx >= 0 && xx < W)
                         ? flat_q[OFFT + (size_t)yy * W + xx] : 0.0f;
        }
    }
    rate_out[OFFT + pos] = arm_mlp_rate(ctx, g[0], w1, b1, w2, b2, wo, bo);
}

// block prefix (256 px/block): cum 6144,7680,8064,8160,8184,8190,8192
__global__ __launch_bounds__(256) void arm_all_kernel(
    const float* __restrict__ flat_q,
    const float* __restrict__ w1, const float* __restrict__ b1,
    const float* __restrict__ w2, const float* __restrict__ b2,
    const float* __restrict__ wo, const float* __restrict__ bo,
    float* __restrict__ rate_out) {
    int b = blockIdx.x;
    int t = threadIdx.x;
    if (b < 6144) {
        arm_body<1024, 1536, OFF0>(flat_q, b * 256 + t, w1, b1, w2, b2, wo, bo, rate_out);
    } else if (b < 7680) {
        arm_body<512, 768, OFF1>(flat_q, (b - 6144) * 256 + t, w1, b1, w2, b2, wo, bo, rate_out);
    } else if (b < 8064) {
        arm_body<256, 384, OFF2>(flat_q, (b - 7680) * 256 + t, w1, b1, w2, b2, wo, bo, rate_out);
    } else if (b < 8160) {
        arm_body<128, 192, OFF3>(flat_q, (b - 8064) * 256 + t, w1, b1, w2, b2, wo, bo, rate_out);
    } else if (b < 8184) {
        arm_body<64, 96, OFF4>(flat_q, (b - 8160) * 256 + t, w1, b1, w2, b2, wo, bo, rate_out);
    } else if (b < 8190) {
        arm_body<32, 48, OFF5>(flat_q, (b - 8184) * 256 + t, w1, b1, w2, b2, wo, bo, rate_out);
    } else {
        arm_body<16, 24, OFF6>(flat_q, (b - 8190) * 256 + t, w1, b1, w2, b2, wo, bo, rate_out);
    }
}

// ---------------- quad helpers ----------------
__device__ __forceinline__ void up_quad(const float* __restrict__ in, int H, int W,
                                        int i, int j, const float* K, float o[4]) {
    float w[5][5];
    bool interior = (i >= 2 && i <= H - 3 && j >= 2 && j <= W - 3);
    if (interior) {
        const float* p = in + (i - 2) * W + (j - 2);
#pragma unroll
        for (int r = 0; r < 5; r++) {
            f4 a = *(const f4*)p;
            w[r][0] = a.x; w[r][1] = a.y; w[r][2] = a.z; w[r][3] = a.w;
            w[r][4] = p[4];
            p += W;
        }
    } else {
#pragma unroll
        for (int r = 0; r < 5; r++)
#pragma unroll
            for (int e = 0; e < 5; e++) {
                int yy = i - 2 + r, xx = j - 2 + e;
                w[r][e] = (yy >= 0 && yy < H && xx >= 0 && xx < W) ? in[yy * W + xx] : 0.0f;
            }
    }
    float h0[5], h1[5];
#pragma unroll
    for (int r = 0; r < 5; r++) {
        h0[r] = K[0]*w[r][0] + K[2]*w[r][1] + K[4]*w[r][2] + K[6]*w[r][3];
        h1[r] = K[1]*w[r][1] + K[3]*w[r][2] + K[5]*w[r][3] + K[7]*w[r][4];
    }
    o[0] = K[0]*h0[0] + K[2]*h0[1] + K[4]*h0[2] + K[6]*h0[3];
    o[1] = K[0]*h1[0] + K[2]*h1[1] + K[4]*h1[2] + K[6]*h1[3];
    o[2] = K[1]*h0[1] + K[3]*h0[2] + K[5]*h0[3] + K[7]*h0[4];
    o[3] = K[1]*h1[1] + K[3]*h1[2] + K[5]*h1[3] + K[7]*h1[4];
}

__device__ __forceinline__ void conv7_quad(const float* __restrict__ dec, int H, int W,
                                           int i, int j, const float* k, float o[4]) {
    int Y = 2 * i, X = 2 * j;
    float g0[8], g1[8];
    bool interior = (Y - 3 >= 0 && Y + 4 <= H - 1 && X - 3 >= 0 && X + 4 <= W - 1);
    if (interior) {
        const float* p = dec + (Y - 3) * W + (X - 3);
#pragma unroll
        for (int r = 0; r < 8; r++) {
            f4 a = *(const f4*)p;
            f4 b = *(const f4*)(p + 4);
            g0[r] = k[0]*a.x + k[1]*a.y + k[2]*a.z + k[3]*a.w + k[4]*b.x + k[5]*b.y + k[6]*b.z;
            g1[r] = k[0]*a.y + k[1]*a.z + k[2]*a.w + k[3]*b.x + k[4]*b.y + k[5]*b.z + k[6]*b.w;
            p += W;
        }
    } else {
#pragma unroll
        for (int r = 0; r < 8; r++) {
            float wv[8];
#pragma unroll
            for (int q = 0; q < 8; q++) {
                int yy = Y - 3 + r, xx = X - 3 + q;
                wv[q] = (yy >= 0 && yy < H && xx >= 0 && xx < W) ? dec[yy * W + xx] : 0.0f;
            }
            g0[r] = k[0]*wv[0] + k[1]*wv[1] + k[2]*wv[2] + k[3]*wv[3] + k[4]*wv[4] + k[5]*wv[5] + k[6]*wv[6];
            g1[r] = k[0]*wv[1] + k[1]*wv[2] + k[2]*wv[3] + k[3]*wv[4] + k[4]*wv[5] + k[5]*wv[6] + k[6]*wv[7];
        }
    }
    o[0] = k[0]*g0[0] + k[1]*g0[1] + k[2]*g0[2] + k[3]*g0[3] + k[4]*g0[4] + k[5]*g0[5] + k[6]*g0[6];
    o[1] = k[0]*g1[0] + k[1]*g1[1] + k[2]*g1[2] + k[3]*g1[3] + k[4]*g1[4] + k[5]*g1[5] + k[6]*g1[6];
    o[2] = k[0]*g0[1] + k[1]*g0[2] + k[2]*g0[3] + k[3]*g0[4] + k[4]*g0[5] + k[5]*g0[6] + k[6]*g0[7];
    o[3] = k[0]*g1[1] + k[1]*g1[2] + k[2]*g1[3] + k[3]*g1[4] + k[4]*g1[5] + k[5]*g1[6] + k[6]*g1[7];
}

// ---------------- pyramid steps (quad per thread) ----------------
__global__ void pyramid_quad_kernel(const float* __restrict__ xin, int hin, int win_,
                                    const float* __restrict__ dec,
                                    const float* __restrict__ upsk, const float* __restrict__ prek,
                                    float* __restrict__ xout, int hout, int wout) {
    int qw = wout >> 1, qh = hout >> 1;
    int j = blockIdx.x * blockDim.x + threadIdx.x;
    int i = blockIdx.y * blockDim.y + threadIdx.y;
    int c = blockIdx.z;
    if (j >= qw || i >= qh) return;
    float o[4];
    if (c == 0) {
        float k[7];
#pragma unroll
        for (int p = 0; p < 7; p++) k[p] = prek[p];
        conv7_quad(dec, hout, wout, i, j, k, o);
    } else {
        float K[8];
#pragma unroll
        for (int p = 0; p < 8; p++) K[p] = upsk[p];
        up_quad(xin + (size_t)(c - 1) * hin * win_, hin, win_, i, j, K, o);
    }
    size_t base = ((size_t)c * hout + 2 * i) * wout + 2 * j;
    *(float2*)(xout + base)        = make_float2(o[0], o[1]);
    *(float2*)(xout + base + wout) = make_float2(o[2], o[3]);
}

// ---------------- final: fused last pyramid step + synthesis, vertical-pair per thread ----------------
__global__ __launch_bounds__(256) void final_kernel(
    const float* __restrict__ up_in,  // 6 ch @ 512x768
    const float* __restrict__ dec0,   // 1024x1536
    const float* __restrict__ upsk, const float* __restrict__ prek,
    const unsigned* __restrict__ wp,  // packed f16x2 weights
    const float* __restrict__ b2,
    float* __restrict__ out) {
    const int H2_ = 512, W2_ = 768, H1_ = 1024, W1_ = 1536;
    int t = threadIdx.x;
    int X  = blockIdx.x * 64 + (t & 63);   // col [0,1536)
    int ip = blockIdx.y * 4 + (t >> 6);    // row-pair [0,512)
    int Y = 2 * ip;

    float K[8], kp[7];
#pragma unroll
    for (int p = 0; p < 8; p++) K[p] = upsk[p];
#pragma unroll
    for (int p = 0; p < 7; p++) kp[p] = prek[p];

    float pxe[7], pxo[7];

    // conv7 ch0, vertical pair
    {
        float g[8];
        bool interior = (Y >= 4 && Y <= H1_ - 6 && X >= 3 && X <= W1_ - 5);
        if (interior) {
            const float* p = dec0 + (size_t)(Y - 3) * W1_ + (X - 3);
#pragma unroll
            for (int r = 0; r < 8; r++) {
                f4 a = *(const f4*)p;
                f4 b = *(const f4*)(p + 4);
                g[r] = kp[0]*a.x + kp[1]*a.y + kp[2]*a.z + kp[3]*a.w
                     + kp[4]*b.x + kp[5]*b.y + kp[6]*b.z;
                p += W1_;
            }
        } else {
#pragma unroll
            for (int r = 0; r < 8; r++) {
                float s = 0.0f;
#pragma unroll
                for (int q = 0; q < 7; q++) {
                    int yy = Y - 3 + r, xx = X - 3 + q;
                    float v = (yy >= 0 && yy < H1_ && xx >= 0 && xx < W1_)
                                  ? dec0[(size_t)yy * W1_ + xx] : 0.0f;
                    s = fmaf(kp[q], v, s);
                }
                g[r] = s;
            }
        }
        float oe = 0.0f, oo = 0.0f;
#pragma unroll
        for (int r = 0; r < 7; r++) {
            oe = fmaf(kp[r], g[r], oe);
            oo = fmaf(kp[r], g[r + 1], oo);
        }
        pxe[0] = oe; pxo[0] = oo;
    }

    // up channels, vertical pair (fixed col parity)
    {
        int q0 = X & 1;
        int j0 = (X >> 1) - 2 + q0;
        float kh[4], kv0[4], kv1[4];
#pragma unroll
        for (int e = 0; e < 4; e++) {
            kh[e]  = K[2 * e + q0];
            kv0[e] = K[2 * e];
            kv1[e] = K[2 * e + 1];
        }
        bool interior = (ip >= 2 && ip <= H2_ - 3 && j0 >= 0 && j0 + 3 < W2_);
#pragma unroll
        for (int c = 0; c < 6; c++) {
            const float* base = up_in + (size_t)c * (H2_ * W2_);
            float h[5];
            if (interior) {
                const float* p = base + (size_t)(ip - 2) * W2_ + j0;
#pragma unroll
                for (int r = 0; r < 5; r++) {
                    f4 a = *(const f4*)p;
                    h[r] = kh[0]*a.x + kh[1]*a.y + kh[2]*a.z + kh[3]*a.w;
                    p += W2_;
                }
            } else {
#pragma unroll
                for (int r = 0; r < 5; r++) {
                    float s = 0.0f;
#pragma unroll
                    for (int e = 0; e < 4; e++) {
                        int yy = ip - 2 + r, xx = j0 + e;
                        float v = (yy >= 0 && yy < H2_ && xx >= 0 && xx < W2_)
                                      ? base[(size_t)yy * W2_ + xx] : 0.0f;
                        s = fmaf(kh[e], v, s);
                    }
                    h[r] = s;
                }
            }
            pxe[c + 1] = kv0[0]*h[0] + kv0[1]*h[1] + kv0[2]*h[2] + kv0[3]*h[3];
            pxo[c + 1] = kv1[0]*h[1] + kv1[1]*h[2] + kv1[2]*h[3] + kv1[3]*h[4];
        }
    }

    // synthesis MLP (fdot2), 2 px — setprio around the pure-VALU burst
    h2 ppe[4], ppo[4];
#pragma unroll
    for (int c = 0; c < 3; c++) {
        ppe[c] = pkrtz(pxe[2 * c], pxe[2 * c + 1]);
        ppo[c] = pkrtz(pxo[2 * c], pxo[2 * c + 1]);
    }
    ppe[3] = pkrtz(pxe[6], 1.0f);
    ppo[3] = pkrtz(pxo[6], 1.0f);

    float acce[6], acco[6];
#pragma unroll
    for (int o = 0; o < 6; o++) { acce[o] = b2[o]; acco[o] = b2[o]; }
    const unsigned* w1p = wp;
    const unsigned* w2p = wp + 192;
    __builtin_amdgcn_s_setprio(1);
#pragma unroll 8
    for (int kk = 0; kk < 24; kk++) {
        h2 wk0[4], wk1[4];
#pragma unroll
        for (int p = 0; p < 4; p++) {
            wk0[p] = as_h2(w1p[(2 * kk) * 4 + p]);
            wk1[p] = as_h2(w1p[(2 * kk + 1) * 4 + p]);
        }
        float s0e = 0.0f, s1e = 0.0f, s0o = 0.0f, s1o = 0.0f;
#pragma unroll
        for (int p = 0; p < 4; p++) {
            s0e = dot2f(wk0[p], ppe[p], s0e);
            s1e = dot2f(wk1[p], ppe[p], s1e);
            s0o = dot2f(wk0[p], ppo[p], s0o);
            s1o = dot2f(wk1[p], ppo[p], s1o);
        }
        h2 hpe = pkrtz(fmaxf(s0e, 0.0f), fmaxf(s1e, 0.0f));
        h2 hpo = pkrtz(fmaxf(s0o, 0.0f), fmaxf(s1o, 0.0f));
#pragma unroll
        for (int o = 0; o < 6; o++) {
            h2 w2k = as_h2(w2p[o * 24 + kk]);
            acce[o] = dot2f(w2k, hpe, acce[o]);
            acco[o] = dot2f(w2k, hpo, acco[o]);
        }
    }
    __builtin_amdgcn_s_setprio(0);

    size_t pe = (size_t)Y * W1_ + X;
    size_t po = pe + W1_;
#pragma unroll
    for (int c = 0; c < 3; c++) {
        out[(size_t)c * HWF + pe] = acce[c];
        out[(size_t)c * HWF + po] = acco[c];
        out[OUT_LS + (size_t)c * HWF + pe] = acce[c + 3];
        out[OUT_LS + (size_t)c * HWF + po] = acco[c + 3];
        out[OUT_DEC + (size_t)c * HWF + pe] = fminf(fmaxf(acce[c], 0.0f), 1.0f);
        out[OUT_DEC + (size_t)c * HWF + po] = fminf(fmaxf(acco[c], 0.0f), 1.0f);
    }
}

// ---------------- launch ----------------
extern "C" void kernel_launch(void* const* d_in, const int* in_sizes, int n_in,
                              void* d_out, int out_size, void* d_ws, size_t ws_size,
                              hipStream_t stream) {
    const float* lat[7];
    for (int i = 0; i < 7; i++) lat[i] = (const float*)d_in[i];
    const float* noise  = (const float*)d_in[7];
    const float* arm_w1 = (const float*)d_in[8];
    const float* arm_b1 = (const float*)d_in[9];
    const float* arm_w2 = (const float*)d_in[10];
    const float* arm_b2 = (const float*)d_in[11];
    const float* arm_wo = (const float*)d_in[12];
    const float* arm_bo = (const float*)d_in[13];
    const float* ups_k  = (const float*)d_in[14]; // (6,8)
    const float* pre_k  = (const float*)d_in[15]; // (6,7)
    const float* syn_w1 = (const float*)d_in[16]; // (48,7)
    const float* syn_b1 = (const float*)d_in[17];
    const float* syn_w2 = (const float*)d_in[18]; // (6,48)
    const float* syn_b2 = (const float*)d_in[19];
    float* out = (float*)d_out;

    // workspace layout (floats)
    float* flat_q = (float*)d_ws;                   // N_TOTAL
    float* bufA   = flat_q + N_TOTAL;               // 6*512*768
    float* bufB   = bufA + 6 * 512 * 768;           // 5*256*384
    unsigned* wpack = (unsigned*)(bufB + 5 * 256 * 384); // 336 u32

    static const int SH[7]  = {1024, 512, 256, 128, 64, 32, 16};
    static const int SW[7]  = {1536, 768, 384, 192, 96, 48, 24};
    static const int OFF[7] = {OFF0, OFF1, OFF2, OFF3, OFF4, OFF5, OFF6};

    // 1. quantization + weight pack
    quant_pack_kernel<<<(N_TOTAL / 4 + 255) / 256, 256, 0, stream>>>(
        lat[0], lat[1], lat[2], lat[3], lat[4], lat[5], lat[6], noise, flat_q,
        syn_w1, syn_b1, syn_w2, wpack);

    // 2. fused ARM + rate
    arm_all_kernel<<<8192, 256, 0, stream>>>(flat_q, arm_w1, arm_b1, arm_w2, arm_b2,
                                             arm_wo, arm_bo, out + OUT_RATE);

    // 3. intermediate pyramid steps s=0..4 (quad kernels), ping-pong bufA/bufB
    const float* xin = flat_q + OFF6; // dec[6], 1ch 16x24
    float* bufs[2] = {bufA, bufB};
    for (int s = 0; s < 5; s++) {
        int i    = 6 - s;
        int hin  = SH[i], win_ = SW[i];
        int hout = SH[i - 1], wout = SW[i - 1];
        float* xout = bufs[s & 1];
        dim3 blk(16, 16);
        dim3 grd((wout / 2 + 15) / 16, (hout / 2 + 15) / 16, s + 2);
        pyramid_quad_kernel<<<grd, blk, 0, stream>>>(xin, hin, win_,
                                                     flat_q + OFF[i - 1],
                                                     ups_k + s * 8, pre_k + s * 7,
                                                     xout, hout, wout);
        xin = xout;
    }

    // 4. fused final step + synthesis (vertical-pair, fdot2)
    dim3 fgrd(1536 / 64, 512 / 4);
    final_kernel<<<fgrd, 256, 0, stream>>>(bufA, flat_q,
                                           ups_k + 5 * 8, pre_k + 5 * 7,
                                           wpack, syn_b2, out);
}

// Round 19
// 134.226 us; speedup vs baseline: 1.0073x; 1.0073x over previous
//
#include <hip/hip_runtime.h>
#include <math.h>

// ---------------- problem constants ----------------
#define N_TOTAL 2097024
#define HWF (1024 * 1536)

#define OFF0 0
#define OFF1 1572864
#define OFF2 1966080
#define OFF3 2064384
#define OFF4 2088960
#define OFF5 2095104
#define OFF6 2096640

// output section offsets (floats)
#define OUT_LS   (3 * HWF)
#define OUT_DEC  (6 * HWF)
#define OUT_RATE (9 * HWF)

// vector loads at dword (not natural) alignment
typedef float f4 __attribute__((ext_vector_type(4), aligned(4)));
typedef float f2 __attribute__((ext_vector_type(2), aligned(4)));
typedef float f4a16 __attribute__((ext_vector_type(4), aligned(16)));
typedef _Float16 h2 __attribute__((ext_vector_type(2)));
typedef __fp16 fp16v2 __attribute__((ext_vector_type(2)));

__device__ __forceinline__ h2 as_h2(unsigned u) {
    union { unsigned u; h2 h; } x; x.u = u; return x.h;
}
__device__ __forceinline__ h2 pkrtz(float a, float b) {
    union { fp16v2 f; h2 h; } x;
    x.f = __builtin_amdgcn_cvt_pkrtz(a, b);
    return x.h;
}
__device__ __forceinline__ float dot2f(h2 a, h2 b, float c) {
#if __has_builtin(__builtin_amdgcn_fdot2)
    return __builtin_amdgcn_fdot2(a, b, c, false);
#else
    return fmaf((float)a[0], (float)b[0], fmaf((float)a[1], (float)b[1], c));
#endif
}

// ---------------- softround (fast tanh via v_exp + v_rcp) ----------------
__device__ __forceinline__ float softround_f(float x) {
    const float INV_T = 1.0f / 0.3f;
    const float HALF_OVER_TANH = 0.53699381f; // 0.5 / tanh(0.5/0.3)
    float fl = floorf(x);
    float z = (x - fl - 0.5f) * INV_T;
    float e = __expf(2.0f * z);
    float th = 1.0f - 2.0f * __builtin_amdgcn_rcpf(e + 1.0f);
    return fl + th * HALF_OVER_TANH + 0.5f;
}

// ---------------- kernel 1: quantization (4 elems/thread) + weight pack in block 0 ----------------
__global__ void quant_pack_kernel(const float* __restrict__ l0, const float* __restrict__ l1,
                                  const float* __restrict__ l2, const float* __restrict__ l3,
                                  const float* __restrict__ l4, const float* __restrict__ l5,
                                  const float* __restrict__ l6, const float* __restrict__ noise,
                                  float* __restrict__ flat_q,
                                  const float* __restrict__ sw1, const float* __restrict__ sb1,
                                  const float* __restrict__ sw2, unsigned* __restrict__ wp) {
    int t = threadIdx.x;
    if (blockIdx.x == 0) {
        for (int i = t; i < 336; i += 256) {
            union { h2 h; unsigned u; } c;
            if (i < 192) {
                int k = i >> 2, p = i & 3;
                float x = sw1[k * 7 + 2 * p];
                float y = (p < 3) ? sw1[k * 7 + 2 * p + 1] : sb1[k];
                c.h = (h2){(_Float16)x, (_Float16)y};
            } else {
                int r = i - 192;
                int o = r / 24, kk = r - o * 24;
                c.h = (h2){(_Float16)sw2[o * 48 + 2 * kk], (_Float16)sw2[o * 48 + 2 * kk + 1]};
            }
            wp[i] = c.u;
        }
    }
    int idx = (blockIdx.x * 256 + t) * 4;
    if (idx >= N_TOTAL) return;
    const float* src;
    int base;
    if      (idx < OFF1) { src = l0; base = idx - OFF0; }
    else if (idx < OFF2) { src = l1; base = idx - OFF1; }
    else if (idx < OFF3) { src = l2; base = idx - OFF2; }
    else if (idx < OFF4) { src = l3; base = idx - OFF3; }
    else if (idx < OFF5) { src = l4; base = idx - OFF4; }
    else if (idx < OFF6) { src = l5; base = idx - OFF5; }
    else                 { src = l6; base = idx - OFF6; }
    f4a16 v = *(const f4a16*)(src + base);
    f4a16 n = *(const f4a16*)(noise + idx);
    f4a16 r;
#pragma unroll
    for (int c = 0; c < 4; c++) {
        float x = v[c] * 16.0f;
        float s1 = softround_f(x);
        r[c] = softround_f(s1 + n[c] - 0.5f);
    }
    *(f4a16*)(flat_q + idx) = r;
}

// ---------------- ARM MLP + rate from ctx (unroll 8 for ILP) ----------------
__device__ __forceinline__ float arm_mlp_rate(const float ctx[16], float q,
                                              const float* __restrict__ w1, const float* __restrict__ b1,
                                              const float* __restrict__ w2, const float* __restrict__ b2,
                                              const float* __restrict__ wo, const float* __restrict__ bo) {
    float h1[16];
#pragma unroll 8
    for (int j = 0; j < 16; j++) {
        float acc = b1[j] + ctx[j];
#pragma unroll
        for (int k = 0; k < 16; k++) acc = fmaf(w1[j * 16 + k], ctx[k], acc);
        h1[j] = fmaxf(acc, 0.0f);
    }
    float h2v[16];
#pragma unroll 8
    for (int j = 0; j < 16; j++) {
        float acc = b2[j] + h1[j];
#pragma unroll
        for (int k = 0; k < 16; k++) acc = fmaf(w2[j * 16 + k], h1[k], acc);
        h2v[j] = fmaxf(acc, 0.0f);
    }
    float mu = bo[0], ls = bo[1];
#pragma unroll
    for (int k = 0; k < 16; k++) {
        mu = fmaf(wo[k], h2v[k], mu);
        ls = fmaf(wo[16 + k], h2v[k], ls);
    }
    ls = fminf(fmaxf(ls, -13.8155f), 13.8155f);
    float inv_scale = __expf(0.5f * ls);
    float da = (q + 0.5f) - mu;
    float db = (q - 0.5f) - mu;
    float ea = __expf(-fabsf(da) * inv_scale);
    float eb = __expf(-fabsf(db) * inv_scale);
    float la = 0.5f - 0.5f * copysignf(1.0f, da) * (ea - 1.0f);
    float lb = 0.5f - 0.5f * copysignf(1.0f, db) * (eb - 1.0f);
    float proba = fmaxf(la - lb, 1.52587890625e-05f);
    return -__log2f(proba);
}

// ---------------- ARM body (vectorized context rows) ----------------
template <int H, int W, int OFFT>
__device__ __forceinline__ void arm_body(const float* __restrict__ flat_q, int pos,
                                         const float* __restrict__ w1, const float* __restrict__ b1,
                                         const float* __restrict__ w2, const float* __restrict__ b2,
                                         const float* __restrict__ wo, const float* __restrict__ bo,
                                         float* __restrict__ rate_out) {
    if (pos >= H * W) return;
    unsigned up = (unsigned)pos;
    int y = up / (unsigned)W;
    int x = pos - y * W;
    const float* g = flat_q + OFFT + (size_t)y * W + x;

    float ctx[16];
    if (y >= 3 && x >= 3 && x <= W - 3) {
        f4 r3  = *(const f4*)(g - 3 * W - 1);
        f4 r2a = *(const f4*)(g - 2 * W - 2);
        float r2b = g[-2 * W + 2];
        f4 r1a = *(const f4*)(g - W - 3);
        f2 r1b = *(const f2*)(g - W + 1);
        f2 r0  = *(const f2*)(g - 2);
        ctx[0] = r3.x;  ctx[1] = r3.y;  ctx[2] = r3.z;
        ctx[3] = r2a.x; ctx[4] = r2a.y; ctx[5] = r2a.z; ctx[6] = r2a.w; ctx[7] = r2b;
        ctx[8] = r1a.x; ctx[9] = r1a.y; ctx[10] = r1a.z; ctx[11] = r1a.w;
        ctx[12] = r1b.x; ctx[13] = r1b.y;
        ctx[14] = r0.x; ctx[15] = r0.y;
    } else {
        const int DY[16] = {-3,-3,-3,-2,-2,-2,-2,-2,-1,-1,-1,-1,-1,-1, 0, 0};
        const int DX[16] = {-1, 0, 1,-2,-1, 0, 1, 2,-3,-2,-1, 0, 1, 2,-2,-1};
#pragma unroll
        for (int k = 0; k < 16; k++) {
            int yy = y + DY[k], xx = x + DX[k];
            ctx[k] = (yy >= 0 && yy < H && xx >= 0 && xx < W)
                         ? flat_q[OFFT + (size_t)yy * W + xx] : 0.0f;
        }
    }
    rate_out[OFFT + pos] = arm_mlp_rate(ctx, g[0], w1, b1, w2, b2, wo, bo);
}

// block prefix (256 px/block): cum 6144,7680,8064,8160,8184,8190,8192
__global__ __launch_bounds__(256) void arm_all_kernel(
    const float* __restrict__ flat_q,
    const float* __restrict__ w1, const float* __restrict__ b1,
    const float* __restrict__ w2, const float* __restrict__ b2,
    const float* __restrict__ wo, const float* __restrict__ bo,
    float* __restrict__ rate_out) {
    int b = blockIdx.x;
    int t = threadIdx.x;
    if (b < 6144) {
        arm_body<1024, 1536, OFF0>(flat_q, b * 256 + t, w1, b1, w2, b2, wo, bo, rate_out);
    } else if (b < 7680) {
        arm_body<512, 768, OFF1>(flat_q, (b - 6144) * 256 + t, w1, b1, w2, b2, wo, bo, rate_out);
    } else if (b < 8064) {
        arm_body<256, 384, OFF2>(flat_q, (b - 7680) * 256 + t, w1, b1, w2, b2, wo, bo, rate_out);
    } else if (b < 8160) {
        arm_body<128, 192, OFF3>(flat_q, (b - 8064) * 256 + t, w1, b1, w2, b2, wo, bo, rate_out);
    } else if (b < 8184) {
        arm_body<64, 96, OFF4>(flat_q, (b - 8160) * 256 + t, w1, b1, w2, b2, wo, bo, rate_out);
    } else if (b < 8190) {
        arm_body<32, 48, OFF5>(flat_q, (b - 8184) * 256 + t, w1, b1, w2, b2, wo, bo, rate_out);
    } else {
        arm_body<16, 24, OFF6>(flat_q, (b - 8190) * 256 + t, w1, b1, w2, b2, wo, bo, rate_out);
    }
}

// ---------------- quad helpers ----------------
__device__ __forceinline__ void up_quad(const float* __restrict__ in, int H, int W,
                                        int i, int j, const float* K, float o[4]) {
    float w[5][5];
    bool interior = (i >= 2 && i <= H - 3 && j >= 2 && j <= W - 3);
    if (interior) {
        const float* p = in + (i - 2) * W + (j - 2);
#pragma unroll
        for (int r = 0; r < 5; r++) {
            f4 a = *(const f4*)p;
            w[r][0] = a.x; w[r][1] = a.y; w[r][2] = a.z; w[r][3] = a.w;
            w[r][4] = p[4];
            p += W;
        }
    } else {
#pragma unroll
        for (int r = 0; r < 5; r++)
#pragma unroll
            for (int e = 0; e < 5; e++) {
                int yy = i - 2 + r, xx = j - 2 + e;
                w[r][e] = (yy >= 0 && yy < H && xx >= 0 && xx < W) ? in[yy * W + xx] : 0.0f;
            }
    }
    float h0[5], h1[5];
#pragma unroll
    for (int r = 0; r < 5; r++) {
        h0[r] = K[0]*w[r][0] + K[2]*w[r][1] + K[4]*w[r][2] + K[6]*w[r][3];
        h1[r] = K[1]*w[r][1] + K[3]*w[r][2] + K[5]*w[r][3] + K[7]*w[r][4];
    }
    o[0] = K[0]*h0[0] + K[2]*h0[1] + K[4]*h0[2] + K[6]*h0[3];
    o[1] = K[0]*h1[0] + K[2]*h1[1] + K[4]*h1[2] + K[6]*h1[3];
    o[2] = K[1]*h0[1] + K[3]*h0[2] + K[5]*h0[3] + K[7]*h0[4];
    o[3] = K[1]*h1[1] + K[3]*h1[2] + K[5]*h1[3] + K[7]*h1[4];
}

__device__ __forceinline__ void conv7_quad(const float* __restrict__ dec, int H, int W,
                                           int i, int j, const float* k, float o[4]) {
    int Y = 2 * i, X = 2 * j;
    float g0[8], g1[8];
    bool interior = (Y - 3 >= 0 && Y + 4 <= H - 1 && X - 3 >= 0 && X + 4 <= W - 1);
    if (interior) {
        const float* p = dec + (Y - 3) * W + (X - 3);
#pragma unroll
        for (int r = 0; r < 8; r++) {
            f4 a = *(const f4*)p;
            f4 b = *(const f4*)(p + 4);
            g0[r] = k[0]*a.x + k[1]*a.y + k[2]*a.z + k[3]*a.w + k[4]*b.x + k[5]*b.y + k[6]*b.z;
            g1[r] = k[0]*a.y + k[1]*a.z + k[2]*a.w + k[3]*b.x + k[4]*b.y + k[5]*b.z + k[6]*b.w;
            p += W;
        }
    } else {
#pragma unroll
        for (int r = 0; r < 8; r++) {
            float wv[8];
#pragma unroll
            for (int q = 0; q < 8; q++) {
                int yy = Y - 3 + r, xx = X - 3 + q;
                wv[q] = (yy >= 0 && yy < H && xx >= 0 && xx < W) ? dec[yy * W + xx] : 0.0f;
            }
            g0[r] = k[0]*wv[0] + k[1]*wv[1] + k[2]*wv[2] + k[3]*wv[3] + k[4]*wv[4] + k[5]*wv[5] + k[6]*wv[6];
            g1[r] = k[0]*wv[1] + k[1]*wv[2] + k[2]*wv[3] + k[3]*wv[4] + k[4]*wv[5] + k[5]*wv[6] + k[6]*wv[7];
        }
    }
    o[0] = k[0]*g0[0] + k[1]*g0[1] + k[2]*g0[2] + k[3]*g0[3] + k[4]*g0[4] + k[5]*g0[5] + k[6]*g0[6];
    o[1] = k[0]*g1[0] + k[1]*g1[1] + k[2]*g1[2] + k[3]*g1[3] + k[4]*g1[4] + k[5]*g1[5] + k[6]*g1[6];
    o[2] = k[0]*g0[1] + k[1]*g0[2] + k[2]*g0[3] + k[3]*g0[4] + k[4]*g0[5] + k[5]*g0[6] + k[6]*g0[7];
    o[3] = k[0]*g1[1] + k[1]*g1[2] + k[2]*g1[3] + k[3]*g1[4] + k[4]*g1[5] + k[5]*g1[6] + k[6]*g1[7];
}

// ---------------- pyramid steps (quad per thread) ----------------
__global__ void pyramid_quad_kernel(const float* __restrict__ xin, int hin, int win_,
                                    const float* __restrict__ dec,
                                    const float* __restrict__ upsk, const float* __restrict__ prek,
                                    float* __restrict__ xout, int hout, int wout) {
    int qw = wout >> 1, qh = hout >> 1;
    int j = blockIdx.x * blockDim.x + threadIdx.x;
    int i = blockIdx.y * blockDim.y + threadIdx.y;
    int c = blockIdx.z;
    if (j >= qw || i >= qh) return;
    float o[4];
    if (c == 0) {
        float k[7];
#pragma unroll
        for (int p = 0; p < 7; p++) k[p] = prek[p];
        conv7_quad(dec, hout, wout, i, j, k, o);
    } else {
        float K[8];
#pragma unroll
        for (int p = 0; p < 8; p++) K[p] = upsk[p];
        up_quad(xin + (size_t)(c - 1) * hin * win_, hin, win_, i, j, K, o);
    }
    size_t base = ((size_t)c * hout + 2 * i) * wout + 2 * j;
    *(float2*)(xout + base)        = make_float2(o[0], o[1]);
    *(float2*)(xout + base + wout) = make_float2(o[2], o[3]);
}

// ---------------- final: fused last pyramid step + synthesis, vertical-pair per thread ----------------
__global__ __launch_bounds__(256) void final_kernel(
    const float* __restrict__ up_in,  // 6 ch @ 512x768
    const float* __restrict__ dec0,   // 1024x1536
    const float* __restrict__ upsk, const float* __restrict__ prek,
    const unsigned* __restrict__ wp,  // packed f16x2 weights
    const float* __restrict__ b2,
    float* __restrict__ out) {
    const int H2_ = 512, W2_ = 768, H1_ = 1024, W1_ = 1536;
    int t = threadIdx.x;
    int X  = blockIdx.x * 64 + (t & 63);   // col [0,1536)
    int ip = blockIdx.y * 4 + (t >> 6);    // row-pair [0,512)
    int Y = 2 * ip;

    float K[8], kp[7];
#pragma unroll
    for (int p = 0; p < 8; p++) K[p] = upsk[p];
#pragma unroll
    for (int p = 0; p < 7; p++) kp[p] = prek[p];

    float pxe[7], pxo[7];

    // conv7 ch0, vertical pair
    {
        float g[8];
        bool interior = (Y >= 4 && Y <= H1_ - 6 && X >= 3 && X <= W1_ - 5);
        if (interior) {
            const float* p = dec0 + (size_t)(Y - 3) * W1_ + (X - 3);
#pragma unroll
            for (int r = 0; r < 8; r++) {
                f4 a = *(const f4*)p;
                f4 b = *(const f4*)(p + 4);
                g[r] = kp[0]*a.x + kp[1]*a.y + kp[2]*a.z + kp[3]*a.w
                     + kp[4]*b.x + kp[5]*b.y + kp[6]*b.z;
                p += W1_;
            }
        } else {
#pragma unroll
            for (int r = 0; r < 8; r++) {
                float s = 0.0f;
#pragma unroll
                for (int q = 0; q < 7; q++) {
                    int yy = Y - 3 + r, xx = X - 3 + q;
                    float v = (yy >= 0 && yy < H1_ && xx >= 0 && xx < W1_)
                                  ? dec0[(size_t)yy * W1_ + xx] : 0.0f;
                    s = fmaf(kp[q], v, s);
                }
                g[r] = s;
            }
        }
        float oe = 0.0f, oo = 0.0f;
#pragma unroll
        for (int r = 0; r < 7; r++) {
            oe = fmaf(kp[r], g[r], oe);
            oo = fmaf(kp[r], g[r + 1], oo);
        }
        pxe[0] = oe; pxo[0] = oo;
    }

    // up channels, vertical pair (fixed col parity)
    {
        int q0 = X & 1;
        int j0 = (X >> 1) - 2 + q0;
        float kh[4], kv0[4], kv1[4];
#pragma unroll
        for (int e = 0; e < 4; e++) {
            kh[e]  = K[2 * e + q0];
            kv0[e] = K[2 * e];
            kv1[e] = K[2 * e + 1];
        }
        bool interior = (ip >= 2 && ip <= H2_ - 3 && j0 >= 0 && j0 + 3 < W2_);
#pragma unroll
        for (int c = 0; c < 6; c++) {
            const float* base = up_in + (size_t)c * (H2_ * W2_);
            float h[5];
            if (interior) {
                const float* p = base + (size_t)(ip - 2) * W2_ + j0;
#pragma unroll
                for (int r = 0; r < 5; r++) {
                    f4 a = *(const f4*)p;
                    h[r] = kh[0]*a.x + kh[1]*a.y + kh[2]*a.z + kh[3]*a.w;
                    p += W2_;
                }
            } else {
#pragma unroll
                for (int r = 0; r < 5; r++) {
                    float s = 0.0f;
#pragma unroll
                    for (int e = 0; e < 4; e++) {
                        int yy = ip - 2 + r, xx = j0 + e;
                        float v = (yy >= 0 && yy < H2_ && xx >= 0 && xx < W2_)
                                      ? base[(size_t)yy * W2_ + xx] : 0.0f;
                        s = fmaf(kh[e], v, s);
                    }
                    h[r] = s;
                }
            }
            pxe[c + 1] = kv0[0]*h[0] + kv0[1]*h[1] + kv0[2]*h[2] + kv0[3]*h[3];
            pxo[c + 1] = kv1[0]*h[1] + kv1[1]*h[2] + kv1[2]*h[3] + kv1[3]*h[4];
        }
    }

    // synthesis MLP (fdot2), 2 px
    h2 ppe[4], ppo[4];
#pragma unroll
    for (int c = 0; c < 3; c++) {
        ppe[c] = pkrtz(pxe[2 * c], pxe[2 * c + 1]);
        ppo[c] = pkrtz(pxo[2 * c], pxo[2 * c + 1]);
    }
    ppe[3] = pkrtz(pxe[6], 1.0f);
    ppo[3] = pkrtz(pxo[6], 1.0f);

    float acce[6], acco[6];
#pragma unroll
    for (int o = 0; o < 6; o++) { acce[o] = b2[o]; acco[o] = b2[o]; }
    const unsigned* w1p = wp;
    const unsigned* w2p = wp + 192;
#pragma unroll 8
    for (int kk = 0; kk < 24; kk++) {
        h2 wk0[4], wk1[4];
#pragma unroll
        for (int p = 0; p < 4; p++) {
            wk0[p] = as_h2(w1p[(2 * kk) * 4 + p]);
            wk1[p] = as_h2(w1p[(2 * kk + 1) * 4 + p]);
        }
        float s0e = 0.0f, s1e = 0.0f, s0o = 0.0f, s1o = 0.0f;
#pragma unroll
        for (int p = 0; p < 4; p++) {
            s0e = dot2f(wk0[p], ppe[p], s0e);
            s1e = dot2f(wk1[p], ppe[p], s1e);
            s0o = dot2f(wk0[p], ppo[p], s0o);
            s1o = dot2f(wk1[p], ppo[p], s1o);
        }
        h2 hpe = pkrtz(fmaxf(s0e, 0.0f), fmaxf(s1e, 0.0f));
        h2 hpo = pkrtz(fmaxf(s0o, 0.0f), fmaxf(s1o, 0.0f));
#pragma unroll
        for (int o = 0; o < 6; o++) {
            h2 w2k = as_h2(w2p[o * 24 + kk]);
            acce[o] = dot2f(w2k, hpe, acce[o]);
            acco[o] = dot2f(w2k, hpo, acco[o]);
        }
    }

    size_t pe = (size_t)Y * W1_ + X;
    size_t po = pe + W1_;
#pragma unroll
    for (int c = 0; c < 3; c++) {
        out[(size_t)c * HWF + pe] = acce[c];
        out[(size_t)c * HWF + po] = acco[c];
        out[OUT_LS + (size_t)c * HWF + pe] = acce[c + 3];
        out[OUT_LS + (size_t)c * HWF + po] = acco[c + 3];
        out[OUT_DEC + (size_t)c * HWF + pe] = fminf(fmaxf(acce[c], 0.0f), 1.0f);
        out[OUT_DEC + (size_t)c * HWF + po] = fminf(fmaxf(acco[c], 0.0f), 1.0f);
    }
}

// ---------------- launch ----------------
extern "C" void kernel_launch(void* const* d_in, const int* in_sizes, int n_in,
                              void* d_out, int out_size, void* d_ws, size_t ws_size,
                              hipStream_t stream) {
    const float* lat[7];
    for (int i = 0; i < 7; i++) lat[i] = (const float*)d_in[i];
    const float* noise  = (const float*)d_in[7];
    const float* arm_w1 = (const float*)d_in[8];
    const float* arm_b1 = (const float*)d_in[9];
    const float* arm_w2 = (const float*)d_in[10];
    const float* arm_b2 = (const float*)d_in[11];
    const float* arm_wo = (const float*)d_in[12];
    const float* arm_bo = (const float*)d_in[13];
    const float* ups_k  = (const float*)d_in[14]; // (6,8)
    const float* pre_k  = (const float*)d_in[15]; // (6,7)
    const float* syn_w1 = (const float*)d_in[16]; // (48,7)
    const float* syn_b1 = (const float*)d_in[17];
    const float* syn_w2 = (const float*)d_in[18]; // (6,48)
    const float* syn_b2 = (const float*)d_in[19];
    float* out = (float*)d_out;

    // workspace layout (floats)
    float* flat_q = (float*)d_ws;                   // N_TOTAL
    float* bufA   = flat_q + N_TOTAL;               // 6*512*768
    float* bufB   = bufA + 6 * 512 * 768;           // 5*256*384
    unsigned* wpack = (unsigned*)(bufB + 5 * 256 * 384); // 336 u32

    static const int SH[7]  = {1024, 512, 256, 128, 64, 32, 16};
    static const int SW[7]  = {1536, 768, 384, 192, 96, 48, 24};
    static const int OFF[7] = {OFF0, OFF1, OFF2, OFF3, OFF4, OFF5, OFF6};

    // 1. quantization + weight pack
    quant_pack_kernel<<<(N_TOTAL / 4 + 255) / 256, 256, 0, stream>>>(
        lat[0], lat[1], lat[2], lat[3], lat[4], lat[5], lat[6], noise, flat_q,
        syn_w1, syn_b1, syn_w2, wpack);

    // 2. fused ARM + rate
    arm_all_kernel<<<8192, 256, 0, stream>>>(flat_q, arm_w1, arm_b1, arm_w2, arm_b2,
                                             arm_wo, arm_bo, out + OUT_RATE);

    // 3. intermediate pyramid steps s=0..4 (quad kernels), ping-pong bufA/bufB
    const float* xin = flat_q + OFF6; // dec[6], 1ch 16x24
    float* bufs[2] = {bufA, bufB};
    for (int s = 0; s < 5; s++) {
        int i    = 6 - s;
        int hin  = SH[i], win_ = SW[i];
        int hout = SH[i - 1], wout = SW[i - 1];
        float* xout = bufs[s & 1];
        dim3 blk(16, 16);
        dim3 grd((wout / 2 + 15) / 16, (hout / 2 + 15) / 16, s + 2);
        pyramid_quad_kernel<<<grd, blk, 0, stream>>>(xin, hin, win_,
                                                     flat_q + OFF[i - 1],
                                                     ups_k + s * 8, pre_k + s * 7,
                                                     xout, hout, wout);
        xin = xout;
    }

    // 4. fused final step + synthesis (vertical-pair, fdot2)
    dim3 fgrd(1536 / 64, 512 / 4);
    final_kernel<<<fgrd, 256, 0, stream>>>(bufA, flat_q,
                                           ups_k + 5 * 8, pre_k + 5 * 7,
                                           wpack, syn_b2, out);
}